// Round 18
// baseline (191.214 us; speedup 1.0000x reference)
//
#include <hip/hip_runtime.h>

#define EMB 2048
#define NH 16
#define NKV 4
#define HD 128
#define SLEN 2048
#define BSZ 2
#define MROWS (BSZ * SLEN) // 4096

// element offsets within the fused QKV output buffer
#define QOFF (BSZ * NH * SLEN * HD)   // 8388608
#define KOFF (BSZ * NKV * SLEN * HD)  // 2097152

typedef __attribute__((ext_vector_type(8))) short bf16x8;
typedef __attribute__((ext_vector_type(4))) float f32x4;
typedef __attribute__((ext_vector_type(2))) float f32x2;
typedef __attribute__((ext_vector_type(4))) short s16x4;

__device__ __forceinline__ short f2bf(float f) {
  union { float f; unsigned u; } v; v.f = f;
  unsigned r = (v.u + 0x7fffu + ((v.u >> 16) & 1u)) >> 16;
  return (short)r;
}

// ---------------- fused prep: cast + rope table + 4 weight transposes -------
#define PB0 8192
#define PB1 (PB0 + 512)
#define PB2 (PB1 + 4096)
#define PB3 (PB2 + 1024)
#define PB4 (PB3 + 1024)
#define PB5 (PB4 + 4096)

__global__ __launch_bounds__(256) void prep_k(
    const float* __restrict__ x, const float* __restrict__ wq,
    const float* __restrict__ wk, const float* __restrict__ wv,
    const float* __restrict__ wo, f32x2* __restrict__ rope,
    short* __restrict__ xb, short* __restrict__ wqkvT, short* __restrict__ woT) {
  int bid = blockIdx.x, tid = threadIdx.x;
  if (bid < PB0) { // cast: 8192 blocks x 256 thr x 4 elems = 4096*2048
    int i = (bid * 256 + tid) * 4;
    f32x4 v = *(const f32x4*)(x + i);
    s16x4 r;
#pragma unroll
    for (int k = 0; k < 4; ++k) r[k] = f2bf(v[k]);
    *(s16x4*)(xb + i) = r;
    return;
  }
  if (bid < PB1) { // rope table: [SLEN][64]
    int i = (bid - PB0) * 256 + tid;
    int s = i >> 6, j = i & 63;
    float freq = exp2f(-(float)j * (13.287712379549449f / 64.0f));
    float ang = (float)s * freq;
    float sv, cv;
    sincosf(ang, &sv, &cv);
    f32x2 cs; cs[0] = cv; cs[1] = sv;
    rope[i] = cs;
    return;
  }
  const float* src; int C, local; short* dst;
  if (bid < PB2)      { src = wq; C = 2048; local = bid - PB1; dst = wqkvT; }
  else if (bid < PB3) { src = wk; C = 512;  local = bid - PB2; dst = wqkvT + 2048 * 2048; }
  else if (bid < PB4) { src = wv; C = 512;  local = bid - PB3; dst = wqkvT + 2560 * 2048; }
  else                { src = wo; C = 2048; local = bid - PB4; dst = woT; }
  __shared__ float t[32][33];
  int nbx = C >> 5;
  int c0 = (local % nbx) * 32, r0 = (local / nbx) * 32;
  int tx = tid & 31, ty = tid >> 5; // 32 x 8
#pragma unroll
  for (int i = 0; i < 4; ++i)
    t[ty + i * 8][tx] = src[(size_t)(r0 + ty + i * 8) * C + (c0 + tx)];
  __syncthreads();
#pragma unroll
  for (int i = 0; i < 4; ++i)
    dst[(size_t)(c0 + ty + i * 8) * 2048 + (r0 + tx)] = f2bf(t[tx][ty + i * 8]);
}

#define GLL16(g, l)                                                        \
  __builtin_amdgcn_global_load_lds(                                        \
      (const __attribute__((address_space(1))) void*)(g),                  \
      (__attribute__((address_space(3))) void*)(l), 16, 0, 0)

// ---------------- 256x128 GEMM, BK=32, ring-3 counted-vmcnt (R18) -----------
// R17 post-mortem: both GEMMs are L2-BW-bound (128x128 = 1.5GB L2->LDS for
// QKV, 44us floor of the 78.6us dispatch). BM=256 cuts traffic per output
// 1.33x: QKV 576MB (16.7us floor), out-proj 384MB. Schedule unchanged:
// per K-step vmcnt(3) + s_barrier only (counted); stage(t+2) issued between
// ds_reads and MFMA. 512 thr / 8 waves (4M x 2N, 64x64 each -> same
// acc[4][4] inner loop). LDS 3 x (16K A + 8K B) = 72KB -> 2 blocks/CU.
// Swizzle (R16): XOR (row>>1)&3 -> 0 conflicts. Transposed grid (x=m-tile)
// pins A-panels per-XCD.
template <int EPI>
__global__ __launch_bounds__(512, 2) void gemm_bt_k(
    const short* __restrict__ A, const short* __restrict__ Bt,
    float* __restrict__ Cf, short* __restrict__ Cb,
    int M, int N, int K, const f32x2* __restrict__ rope) {
  __shared__ short lA[3][256 * 32]; // 3 slots x 16KB: 256 rows x 64B
  __shared__ short lB[3][128 * 32]; // 3 slots x 8KB: 128 rows x 64B
  int tid = threadIdx.x;
  int lane = tid & 63, wid = tid >> 6;
  int m0 = blockIdx.x * 256, n0 = blockIdx.y * 128; // transposed grid
  int wr = (wid >> 1) * 64, wc = (wid & 1) * 64;    // 4M x 2N waves
  int l16 = lane & 15, lk4 = lane >> 4;
  const int K2B = K * 2;
  const char* Ab = (const char*)A;
  const char* Bb = (const char*)Bt;
  (void)M;

  auto stage = [&](int slot, int k0) {
#pragma unroll
    for (int r = 0; r < 2; ++r) { // A: 16KB = 2 rounds x 512thr x 16B
      int X = tid * 16 + r * 8192;
      int row = X >> 6, cb = X & 63;
      int logical = cb ^ ((((row >> 1) & 3)) << 4); // inverse-swizzled source
      GLL16(Ab + (size_t)(m0 + row) * K2B + k0 * 2 + logical, (char*)&lA[slot][0] + X);
    }
    { // B: 8KB = 1 round x 512thr x 16B
      int X = tid * 16;
      int row = X >> 6, cb = X & 63;
      int logical = cb ^ ((((row >> 1) & 3)) << 4);
      GLL16(Bb + (size_t)(n0 + row) * K2B + k0 * 2 + logical, (char*)&lB[slot][0] + X);
    }
  };
  auto ldA = [&](int slot, int m) {
    int row = wr + m * 16 + l16;
    return *(const bf16x8*)((char*)&lA[slot][0] + row * 64 + ((lk4 * 16) ^ ((((row >> 1) & 3)) << 4)));
  };
  auto ldB = [&](int slot, int n) {
    int row = wc + n * 16 + l16;
    return *(const bf16x8*)((char*)&lB[slot][0] + row * 64 + ((lk4 * 16) ^ ((((row >> 1) & 3)) << 4)));
  };

  f32x4 acc[4][4] = {};
  stage(0, 0);
  stage(1, 32);
  int nk = K / 32;
  for (int t = 0; t < nk; ++t) {
    int slot = t % 3;
    // counted wait: stage(t) retired; stage(t+1)'s 3 loads stay in flight
    if (t + 1 < nk) asm volatile("s_waitcnt vmcnt(3)" ::: "memory");
    else            asm volatile("s_waitcnt vmcnt(0)" ::: "memory");
    __builtin_amdgcn_s_barrier();
    __builtin_amdgcn_sched_barrier(0);
    bf16x8 af[4], bfv[4];
#pragma unroll
    for (int m = 0; m < 4; ++m) af[m] = ldA(slot, m);
#pragma unroll
    for (int n = 0; n < 4; ++n) bfv[n] = ldB(slot, n);
    if (t + 2 < nk) stage(slot == 2 ? 1 : (slot == 1 ? 0 : 2), (t + 2) * 32);
    __builtin_amdgcn_s_setprio(1);
#pragma unroll
    for (int m = 0; m < 4; ++m)
#pragma unroll
      for (int n = 0; n < 4; ++n)
        acc[m][n] = __builtin_amdgcn_mfma_f32_16x16x32_bf16(af[m], bfv[n], acc[m][n], 0, 0, 0);
    __builtin_amdgcn_s_setprio(0);
  }

  const float SCL2E = 0.08838834764831845f * 1.4426950408889634f;
  // epilogue: C/D layout col = lane&15, row = (lane>>4)*4 + reg
#pragma unroll
  for (int m = 0; m < 4; ++m) {
#pragma unroll
    for (int n = 0; n < 4; ++n) {
#pragma unroll
      for (int j = 0; j < 4; ++j) {
        int gm = m0 + wr + m * 16 + lk4 * 4 + j;
        int gc = n0 + wc + n * 16 + l16;
        float v = acc[m][n][j];
        if constexpr (EPI == 0) {
          Cf[(size_t)gm * N + gc] = v;
        } else { // EPI == 5: fused QKV, interleaved RoPE
          int pos = gm & (SLEN - 1), bb = gm >> 11;
          if (gc < 2560) { // Q or K
            float p = __shfl_xor(v, 1); // partner column (d^1), same row
            bool isq = gc < 2048;
            int gcc = isq ? gc : gc - 2048;
            int head = gcc >> 7, d = gcc & 127;
            f32x2 cs = rope[pos * 64 + (d >> 1)];
            float ov = ((d & 1) == 0) ? (v * cs[0] - p * cs[1])
                                      : (p * cs[1] + v * cs[0]);
            if (isq) ov *= SCL2E; // fold attn scale*log2e into Q
            size_t idx = isq
                ? (((size_t)(bb * NH + head) * SLEN + pos) * HD + d)
                : ((size_t)QOFF + ((size_t)(bb * NKV + head) * SLEN + pos) * HD + d);
            Cb[idx] = f2bf(ov);
          } else { // V: transposed per (b,kv): [HD][S]
            int gcc = gc - 2560;
            int head = gcc >> 7, d = gcc & 127;
            Cb[(size_t)QOFF + KOFF + ((size_t)(bb * NKV + head) * HD + d) * SLEN + pos] = f2bf(v);
          }
        }
      }
    }
  }
}

// ---------------- flash attention: balanced pairs + 4-deep counted pipeline --
// R15: 256 flat blocks, group g = fid%8 = (b,kv) -> XCD g; all 32 blocks
// sharing one group's 4MB K/V land on ONE XCD = its L2. 4-deep LDS ring,
// per tile only vmcnt(8) + s_barrier. Balanced pairing: 34 units/block.
__global__ __launch_bounds__(512, 2) void flash_k(
    const short* __restrict__ Qb, const short* __restrict__ Kb,
    const short* __restrict__ Vt, short* __restrict__ O) {
  __shared__ short lK[4][64 * 128];   // 4 x 16KB: 64 key rows x 256B
  __shared__ short lV[4][128 * 64];   // 4 x 16KB: 128 dim rows x 128B
  __shared__ short Plds[8][16][64];   // per-wave P: 16 rows x 128B

  int tid = threadIdx.x, lane = tid & 63, wid = tid >> 6;
  int fid = blockIdx.x;
  int g = fid & 7, w = fid >> 3;           // group -> XCD; w in [0,32)
  int b = g >> 2, kv = g & 3;
  int h = kv + 4 * (w & 3);                // h % 4 == kv (jnp.tile GQA)
  int qp = w >> 2;                         // 0..7
  int l16 = lane & 15, lk4 = lane >> 4;
  int qtA = 15 - qp;                       // 8..15 (heavy)
  int qtB = qp;                            // 0..7  (light)
  int ntA = 2 * (qtA + 1);
  int ntot = ntA + 2 * (qtB + 1);          // == 34 for every block

  const short* qptr = Qb + (size_t)(b * NH + h) * SLEN * HD;
  const char* kg = (const char*)(Kb + (size_t)(b * NKV + kv) * SLEN * HD);
  const char* vg = (const char*)(Vt + (size_t)(b * NKV + kv) * HD * SLEN);

  int qbw = qtA * 128 + wid * 16; // current segment's q-row base for this wave
  bf16x8 aq[4];
#pragma unroll
  for (int c = 0; c < 4; ++c)
    aq[c] = *(const bf16x8*)(qptr + (size_t)(qbw + l16) * HD + c * 32 + lk4 * 8);

  f32x4 o[8] = {};
  float m = -__builtin_inff();
  float lsum = 0.0f;

  char* myP = (char*)&Plds[wid][0][0];
  int swz = (l16 & 7) << 4;   // 3-bit (P and V: 128B rows)
  int swzk = l16 << 4;        // 4-bit (K: 256B rows)

  auto stageKV = [&](int buf, int k0) {
#pragma unroll
    for (int r = 0; r < 2; ++r) { // K: 16KB = 2 rounds x 512 thr x 16B
      int X = tid * 16 + r * 8192;
      int row = X >> 8, cb = X & 255;
      GLL16(kg + (size_t)(k0 + row) * 256 + (cb ^ ((row & 15) << 4)),
            (char*)&lK[buf][0] + X);
    }
#pragma unroll
    for (int r = 0; r < 2; ++r) { // V: 16KB
      int X = tid * 16 + r * 8192;
      int row = X >> 7, cb = X & 127;
      GLL16(vg + (size_t)row * (SLEN * 2) + k0 * 2 + (cb ^ ((row & 7) << 4)),
            (char*)&lV[buf][0] + X);
    }
  };
  auto k0_of = [&](int t) { return (t < ntA ? t : t - ntA) * 64; };

  auto finalize = [&]() {
    float ls = lsum;
    ls += __shfl_xor(ls, 16);
    ls += __shfl_xor(ls, 32);
    float inv = 1.0f / ls;
    size_t ro = ((size_t)(b * SLEN + qbw + l16)) * (NH * HD) + h * HD;
#pragma unroll
    for (int dt = 0; dt < 8; ++dt) {
      s16x4 r;
#pragma unroll
      for (int j = 0; j < 4; ++j) r[j] = f2bf(o[dt][j] * inv);
      *(s16x4*)(O + ro + dt * 16 + lk4 * 4) = r;
    }
  };

  // prologue: fill 3 ring slots (ntot >= 18 always)
  stageKV(0, k0_of(0));
  stageKV(1, k0_of(1));
  stageKV(2, k0_of(2));

  for (int tt = 0; tt < ntot; ++tt) {
    int rem = ntot - 1 - tt;
    if (rem >= 2)      asm volatile("s_waitcnt vmcnt(8)" ::: "memory");
    else if (rem == 1) asm volatile("s_waitcnt vmcnt(4)" ::: "memory");
    else               asm volatile("s_waitcnt vmcnt(0)" ::: "memory");
    __builtin_amdgcn_s_barrier();
    __builtin_amdgcn_sched_barrier(0);

    if (tt == ntA) { // segment switch: flush A, reset state, load Q for B
      finalize();
#pragma unroll
      for (int dt = 0; dt < 8; ++dt) o[dt] = (f32x4){0.f, 0.f, 0.f, 0.f};
      m = -__builtin_inff();
      lsum = 0.0f;
      qbw = qtB * 128 + wid * 16;
#pragma unroll
      for (int c = 0; c < 4; ++c)
        aq[c] = *(const bf16x8*)(qptr + (size_t)(qbw + l16) * HD + c * 32 + lk4 * 8);
    }

    int k0 = k0_of(tt);
    int buf = tt & 3;
    if (k0 < qbw + 16) { // this wave has unmasked keys in this tile
      const char* Kbase = (const char*)&lK[buf][0];
      const char* Vbase = (const char*)&lV[buf][0];
      f32x4 s[4] = {};
      __builtin_amdgcn_s_setprio(1);
#pragma unroll
      for (int c = 0; c < 4; ++c) {
#pragma unroll
        for (int t = 0; t < 4; ++t) {
          bf16x8 bk = *(const bf16x8*)(Kbase + (t * 16 + l16) * 256 + ((c * 64 + lk4 * 16) ^ swzk));
          s[t] = __builtin_amdgcn_mfma_f32_16x16x32_bf16(bk, aq[c], s[t], 0, 0, 0);
        }
      }
      __builtin_amdgcn_s_setprio(0);
      float x[16];
#pragma unroll
      for (int t = 0; t < 4; ++t)
#pragma unroll
        for (int j = 0; j < 4; ++j) x[t * 4 + j] = s[t][j];
      if (k0 + 63 > qbw) { // tile touches this wave's causal diagonal
        int kq = k0 + lk4 * 4 - qbw - l16;
#pragma unroll
        for (int t = 0; t < 4; ++t)
#pragma unroll
          for (int j = 0; j < 4; ++j)
            if (kq + t * 16 + j > 0) x[t * 4 + j] = -3.0e38f;
      }
      float a0 = fmaxf(x[0], x[1]), a1 = fmaxf(x[2], x[3]);
      float a2 = fmaxf(x[4], x[5]), a3 = fmaxf(x[6], x[7]);
      float a4 = fmaxf(x[8], x[9]), a5 = fmaxf(x[10], x[11]);
      float a6 = fmaxf(x[12], x[13]), a7 = fmaxf(x[14], x[15]);
      float b0 = fmaxf(fmaxf(a0, a1), fmaxf(a2, a3));
      float b1 = fmaxf(fmaxf(a4, a5), fmaxf(a6, a7));
      float tm = fmaxf(b0, b1);
      tm = fmaxf(tm, __shfl_xor(tm, 16));
      tm = fmaxf(tm, __shfl_xor(tm, 32));
      float mn = fmaxf(m, tm);
      if (!__all(tm <= m + 8.0f)) { // T13 defer-rescale
        float f = __builtin_amdgcn_exp2f(m - mn);
        m = mn;
        lsum *= f;
#pragma unroll
        for (int dt = 0; dt < 8; ++dt) o[dt] *= f;
      }
      float psum = 0.0f;
#pragma unroll
      for (int t = 0; t < 4; ++t) {
        float p0 = __builtin_amdgcn_exp2f(x[t * 4 + 0] - m);
        float p1 = __builtin_amdgcn_exp2f(x[t * 4 + 1] - m);
        float p2 = __builtin_amdgcn_exp2f(x[t * 4 + 2] - m);
        float p3 = __builtin_amdgcn_exp2f(x[t * 4 + 3] - m);
        psum += (p0 + p1) + (p2 + p3);
        unsigned lo, hi;
        asm("v_cvt_pk_bf16_f32 %0, %1, %2" : "=v"(lo) : "v"(p0), "v"(p1));
        asm("v_cvt_pk_bf16_f32 %0, %1, %2" : "=v"(hi) : "v"(p2), "v"(p3));
        unsigned long long dw = ((unsigned long long)hi << 32) | lo;
        *(unsigned long long*)(myP + ((l16 * 128 + t * 32 + lk4 * 8) ^ swz)) = dw;
      }
      lsum += psum;
      // ---- ORDERING FENCE (rule #18): drain P ds_writes, pin reads below --
      asm volatile("s_waitcnt lgkmcnt(0)" ::: "memory");
      __builtin_amdgcn_sched_barrier(0);
      __builtin_amdgcn_s_setprio(1);
#pragma unroll
      for (int hh = 0; hh < 2; ++hh) {
        bf16x8 pa = *(const bf16x8*)(myP + ((l16 * 128 + hh * 64 + lk4 * 16) ^ swz));
#pragma unroll
        for (int dt = 0; dt < 8; ++dt) {
          bf16x8 bv = *(const bf16x8*)(Vbase + (dt * 16 + l16) * 128 + ((hh * 64 + lk4 * 16) ^ swz));
          o[dt] = __builtin_amdgcn_mfma_f32_16x16x32_bf16(bv, pa, o[dt], 0, 0, 0);
        }
      }
      __builtin_amdgcn_s_setprio(0);
    }
    // issue stage for tile tt+3 into ring slot (tt+3)&3 == (tt-1)&3, whose
    // readers finished before this iteration's opening barrier (no WAR race).
    if (tt + 3 < ntot) stageKV((tt + 3) & 3, k0_of(tt + 3));
  }
  finalize(); // segment B
}

extern "C" void kernel_launch(void* const* d_in, const int* in_sizes, int n_in,
                              void* d_out, int out_size, void* d_ws, size_t ws_size,
                              hipStream_t stream) {
  const float* x  = (const float*)d_in[0];
  const float* wq = (const float*)d_in[1];
  const float* wk = (const float*)d_in[2];
  const float* wv = (const float*)d_in[3];
  const float* wo = (const float*)d_in[4];
  float* out = (float*)d_out;
  char* ws = (char*)d_ws;
  (void)in_sizes; (void)n_in; (void)out_size; (void)ws_size;

  const size_t MB = 1024 * 1024;
  f32x2* rope   = (f32x2*)(ws);          // 1 MB
  short* xb     = (short*)(ws + 1 * MB); // 16 MB (reused as O)
  short* wqkvT  = (short*)(ws + 17 * MB);// 12 MB: [3072][2048] bf16 B^T
  short* woT    = (short*)(ws + 29 * MB);// 8 MB
  short* QKVb   = (short*)(ws + 37 * MB);// 24 MB: Q(16) + K(4) + V(4)
  short* O      = xb;                    // alias: xb dead after QKV GEMM

  short* Qb = QKVb;
  short* Kb = QKVb + QOFF;
  short* Vt = QKVb + QOFF + KOFF;

  prep_k<<<PB5, 256, 0, stream>>>(x, wq, wk, wv, wo, rope, xb, wqkvT, woT);

  gemm_bt_k<5><<<dim3(MROWS / 256, 3072 / 128), 512, 0, stream>>>(xb, wqkvT, nullptr, QKVb, MROWS, 3072, 2048, rope);

  flash_k<<<256, 512, 0, stream>>>(Qb, Kb, Vt, O);

  gemm_bt_k<0><<<dim3(MROWS / 256, 2048 / 128), 512, 0, stream>>>(O, woT, out, nullptr, MROWS, 2048, 2048, rope);
}

// Round 19
// 176.899 us; speedup vs baseline: 1.0809x; 1.0809x over previous
//
#include <hip/hip_runtime.h>

#define EMB 2048
#define NH 16
#define NKV 4
#define HD 128
#define SLEN 2048
#define BSZ 2
#define MROWS (BSZ * SLEN) // 4096

// element offsets within the fused QKV output buffer
#define QOFF (BSZ * NH * SLEN * HD)   // 8388608
#define KOFF (BSZ * NKV * SLEN * HD)  // 2097152

typedef __attribute__((ext_vector_type(8))) short bf16x8;
typedef __attribute__((ext_vector_type(4))) float f32x4;
typedef __attribute__((ext_vector_type(2))) float f32x2;
typedef __attribute__((ext_vector_type(4))) short s16x4;

__device__ __forceinline__ short f2bf(float f) {
  union { float f; unsigned u; } v; v.f = f;
  unsigned r = (v.u + 0x7fffu + ((v.u >> 16) & 1u)) >> 16;
  return (short)r;
}

// ---------------- fused prep: cast + rope table + 4 weight transposes -------
#define PB0 8192
#define PB1 (PB0 + 512)
#define PB2 (PB1 + 4096)
#define PB3 (PB2 + 1024)
#define PB4 (PB3 + 1024)
#define PB5 (PB4 + 4096)

__global__ __launch_bounds__(256) void prep_k(
    const float* __restrict__ x, const float* __restrict__ wq,
    const float* __restrict__ wk, const float* __restrict__ wv,
    const float* __restrict__ wo, f32x2* __restrict__ rope,
    short* __restrict__ xb, short* __restrict__ wqkvT, short* __restrict__ woT) {
  int bid = blockIdx.x, tid = threadIdx.x;
  if (bid < PB0) { // cast: 8192 blocks x 256 thr x 4 elems = 4096*2048
    int i = (bid * 256 + tid) * 4;
    f32x4 v = *(const f32x4*)(x + i);
    s16x4 r;
#pragma unroll
    for (int k = 0; k < 4; ++k) r[k] = f2bf(v[k]);
    *(s16x4*)(xb + i) = r;
    return;
  }
  if (bid < PB1) { // rope table: [SLEN][64]
    int i = (bid - PB0) * 256 + tid;
    int s = i >> 6, j = i & 63;
    float freq = exp2f(-(float)j * (13.287712379549449f / 64.0f));
    float ang = (float)s * freq;
    float sv, cv;
    sincosf(ang, &sv, &cv);
    f32x2 cs; cs[0] = cv; cs[1] = sv;
    rope[i] = cs;
    return;
  }
  const float* src; int C, local; short* dst;
  if (bid < PB2)      { src = wq; C = 2048; local = bid - PB1; dst = wqkvT; }
  else if (bid < PB3) { src = wk; C = 512;  local = bid - PB2; dst = wqkvT + 2048 * 2048; }
  else if (bid < PB4) { src = wv; C = 512;  local = bid - PB3; dst = wqkvT + 2560 * 2048; }
  else                { src = wo; C = 2048; local = bid - PB4; dst = woT; }
  __shared__ float t[32][33];
  int nbx = C >> 5;
  int c0 = (local % nbx) * 32, r0 = (local / nbx) * 32;
  int tx = tid & 31, ty = tid >> 5; // 32 x 8
#pragma unroll
  for (int i = 0; i < 4; ++i)
    t[ty + i * 8][tx] = src[(size_t)(r0 + ty + i * 8) * C + (c0 + tx)];
  __syncthreads();
#pragma unroll
  for (int i = 0; i < 4; ++i)
    dst[(size_t)(c0 + ty + i * 8) * 2048 + (r0 + tx)] = f2bf(t[tx][ty + i * 8]);
}

#define GLL16(g, l)                                                        \
  __builtin_amdgcn_global_load_lds(                                        \
      (const __attribute__((address_space(1))) void*)(g),                  \
      (__attribute__((address_space(3))) void*)(l), 16, 0, 0)

// ---------------- 128x128 GEMM, BK=32, ring-3 counted-vmcnt (R17 best) ------
// Transposed grid (x=m-tile) pins A-panels per-XCD. Per K-step: vmcnt(4) +
// s_barrier only (counted); stage(t+2) issued between ds_reads and MFMA.
// Swizzle XOR (row>>1)&3 -> 0 bank conflicts (R16).
// R19: V-branch of the QKV epilogue packs 4 consecutive-pos bf16 into one
// 8B s16x4 store (per lane, acc[m][n][0..3] = pos, pos+1..3 at fixed d in
// the V^T layout; 4-aligned so no batch-boundary crossing) -> 4x fewer
// scattered V-store instructions.
template <int EPI>
__global__ __launch_bounds__(256, 3) void gemm_bt_k(
    const short* __restrict__ A, const short* __restrict__ Bt,
    float* __restrict__ Cf, short* __restrict__ Cb,
    int M, int N, int K, const f32x2* __restrict__ rope) {
  __shared__ short lA[3][128 * 32]; // 3 slots x 8KB: 128 rows x 64B
  __shared__ short lB[3][128 * 32];
  int tid = threadIdx.x;
  int lane = tid & 63, wid = tid >> 6;
  int m0 = blockIdx.x * 128, n0 = blockIdx.y * 128; // transposed grid
  int wr = (wid >> 1) * 64, wc = (wid & 1) * 64;
  int l16 = lane & 15, lk4 = lane >> 4;
  const int K2B = K * 2;
  const char* Ab = (const char*)A;
  const char* Bb = (const char*)Bt;
  (void)M;

  auto stage = [&](int slot, int k0) {
#pragma unroll
    for (int r = 0; r < 2; ++r) { // 8KB per array = 2 rounds x 256thr x 16B
      int X = tid * 16 + r * 4096;
      int row = X >> 6, cb = X & 63;
      int logical = cb ^ ((((row >> 1) & 3)) << 4); // inverse-swizzled source
      GLL16(Ab + (size_t)(m0 + row) * K2B + k0 * 2 + logical, (char*)&lA[slot][0] + X);
      GLL16(Bb + (size_t)(n0 + row) * K2B + k0 * 2 + logical, (char*)&lB[slot][0] + X);
    }
  };
  auto ldA = [&](int slot, int m) {
    int row = wr + m * 16 + l16;
    return *(const bf16x8*)((char*)&lA[slot][0] + row * 64 + ((lk4 * 16) ^ ((((row >> 1) & 3)) << 4)));
  };
  auto ldB = [&](int slot, int n) {
    int row = wc + n * 16 + l16;
    return *(const bf16x8*)((char*)&lB[slot][0] + row * 64 + ((lk4 * 16) ^ ((((row >> 1) & 3)) << 4)));
  };

  f32x4 acc[4][4] = {};
  stage(0, 0);
  stage(1, 32);
  int nk = K / 32;
  for (int t = 0; t < nk; ++t) {
    int slot = t % 3;
    if (t + 1 < nk) asm volatile("s_waitcnt vmcnt(4)" ::: "memory");
    else            asm volatile("s_waitcnt vmcnt(0)" ::: "memory");
    __builtin_amdgcn_s_barrier();
    __builtin_amdgcn_sched_barrier(0);
    bf16x8 af[4], bfv[4];
#pragma unroll
    for (int m = 0; m < 4; ++m) af[m] = ldA(slot, m);
#pragma unroll
    for (int n = 0; n < 4; ++n) bfv[n] = ldB(slot, n);
    if (t + 2 < nk) stage(slot == 2 ? 1 : (slot == 1 ? 0 : 2), (t + 2) * 32);
    __builtin_amdgcn_s_setprio(1);
#pragma unroll
    for (int m = 0; m < 4; ++m)
#pragma unroll
      for (int n = 0; n < 4; ++n)
        acc[m][n] = __builtin_amdgcn_mfma_f32_16x16x32_bf16(af[m], bfv[n], acc[m][n], 0, 0, 0);
    __builtin_amdgcn_s_setprio(0);
  }

  const float SCL2E = 0.08838834764831845f * 1.4426950408889634f;
  // epilogue: C/D layout col = lane&15, row = (lane>>4)*4 + reg
#pragma unroll
  for (int m = 0; m < 4; ++m) {
#pragma unroll
    for (int n = 0; n < 4; ++n) {
      int gc = n0 + wc + n * 16 + l16;
      if constexpr (EPI == 0) {
#pragma unroll
        for (int j = 0; j < 4; ++j) {
          int gm = m0 + wr + m * 16 + lk4 * 4 + j;
          Cf[(size_t)gm * N + gc] = acc[m][n][j];
        }
      } else { // EPI == 5: fused QKV, interleaved RoPE
        if (gc < 2560) { // Q or K: per-element (stores 32B-contiguous/group)
#pragma unroll
          for (int j = 0; j < 4; ++j) {
            int gm = m0 + wr + m * 16 + lk4 * 4 + j;
            int pos = gm & (SLEN - 1), bb = gm >> 11;
            float v = acc[m][n][j];
            float p = __shfl_xor(v, 1); // partner column (d^1), same row
            bool isq = gc < 2048;
            int gcc = isq ? gc : gc - 2048;
            int head = gcc >> 7, d = gcc & 127;
            f32x2 cs = rope[pos * 64 + (d >> 1)];
            float ov = ((d & 1) == 0) ? (v * cs[0] - p * cs[1])
                                      : (p * cs[1] + v * cs[0]);
            if (isq) ov *= SCL2E; // fold attn scale*log2e into Q
            size_t idx = isq
                ? (((size_t)(bb * NH + head) * SLEN + pos) * HD + d)
                : ((size_t)QOFF + ((size_t)(bb * NKV + head) * SLEN + pos) * HD + d);
            Cb[idx] = f2bf(ov);
          }
        } else { // V: packed 8B store (4 consecutive pos at fixed d)
          int gcc = gc - 2560;
          int head = gcc >> 7, d = gcc & 127;
          int gm0 = m0 + wr + m * 16 + lk4 * 4; // j = 0; 4-aligned
          int pos = gm0 & (SLEN - 1), bb = gm0 >> 11;
          s16x4 r;
#pragma unroll
          for (int j = 0; j < 4; ++j) r[j] = f2bf(acc[m][n][j]);
          *(s16x4*)&Cb[(size_t)QOFF + KOFF +
                       ((size_t)(bb * NKV + head) * HD + d) * SLEN + pos] = r;
        }
      }
    }
  }
}

// ---------------- flash attention: balanced pairs + 4-deep counted pipeline --
// R15: 256 flat blocks, group g = fid%8 = (b,kv) -> XCD g; all 32 blocks
// sharing one group's 4MB K/V land on ONE XCD = its L2. 4-deep LDS ring,
// per tile only vmcnt(8) + s_barrier. Balanced pairing: 34 units/block.
__global__ __launch_bounds__(512, 2) void flash_k(
    const short* __restrict__ Qb, const short* __restrict__ Kb,
    const short* __restrict__ Vt, short* __restrict__ O) {
  __shared__ short lK[4][64 * 128];   // 4 x 16KB: 64 key rows x 256B
  __shared__ short lV[4][128 * 64];   // 4 x 16KB: 128 dim rows x 128B
  __shared__ short Plds[8][16][64];   // per-wave P: 16 rows x 128B

  int tid = threadIdx.x, lane = tid & 63, wid = tid >> 6;
  int fid = blockIdx.x;
  int g = fid & 7, w = fid >> 3;           // group -> XCD; w in [0,32)
  int b = g >> 2, kv = g & 3;
  int h = kv + 4 * (w & 3);                // h % 4 == kv (jnp.tile GQA)
  int qp = w >> 2;                         // 0..7
  int l16 = lane & 15, lk4 = lane >> 4;
  int qtA = 15 - qp;                       // 8..15 (heavy)
  int qtB = qp;                            // 0..7  (light)
  int ntA = 2 * (qtA + 1);
  int ntot = ntA + 2 * (qtB + 1);          // == 34 for every block

  const short* qptr = Qb + (size_t)(b * NH + h) * SLEN * HD;
  const char* kg = (const char*)(Kb + (size_t)(b * NKV + kv) * SLEN * HD);
  const char* vg = (const char*)(Vt + (size_t)(b * NKV + kv) * HD * SLEN);

  int qbw = qtA * 128 + wid * 16; // current segment's q-row base for this wave
  bf16x8 aq[4];
#pragma unroll
  for (int c = 0; c < 4; ++c)
    aq[c] = *(const bf16x8*)(qptr + (size_t)(qbw + l16) * HD + c * 32 + lk4 * 8);

  f32x4 o[8] = {};
  float m = -__builtin_inff();
  float lsum = 0.0f;

  char* myP = (char*)&Plds[wid][0][0];
  int swz = (l16 & 7) << 4;   // 3-bit (P and V: 128B rows)
  int swzk = l16 << 4;        // 4-bit (K: 256B rows)

  auto stageKV = [&](int buf, int k0) {
#pragma unroll
    for (int r = 0; r < 2; ++r) { // K: 16KB = 2 rounds x 512 thr x 16B
      int X = tid * 16 + r * 8192;
      int row = X >> 8, cb = X & 255;
      GLL16(kg + (size_t)(k0 + row) * 256 + (cb ^ ((row & 15) << 4)),
            (char*)&lK[buf][0] + X);
    }
#pragma unroll
    for (int r = 0; r < 2; ++r) { // V: 16KB
      int X = tid * 16 + r * 8192;
      int row = X >> 7, cb = X & 127;
      GLL16(vg + (size_t)row * (SLEN * 2) + k0 * 2 + (cb ^ ((row & 7) << 4)),
            (char*)&lV[buf][0] + X);
    }
  };
  auto k0_of = [&](int t) { return (t < ntA ? t : t - ntA) * 64; };

  auto finalize = [&]() {
    float ls = lsum;
    ls += __shfl_xor(ls, 16);
    ls += __shfl_xor(ls, 32);
    float inv = 1.0f / ls;
    size_t ro = ((size_t)(b * SLEN + qbw + l16)) * (NH * HD) + h * HD;
#pragma unroll
    for (int dt = 0; dt < 8; ++dt) {
      s16x4 r;
#pragma unroll
      for (int j = 0; j < 4; ++j) r[j] = f2bf(o[dt][j] * inv);
      *(s16x4*)(O + ro + dt * 16 + lk4 * 4) = r;
    }
  };

  // prologue: fill 3 ring slots (ntot >= 18 always)
  stageKV(0, k0_of(0));
  stageKV(1, k0_of(1));
  stageKV(2, k0_of(2));

  for (int tt = 0; tt < ntot; ++tt) {
    int rem = ntot - 1 - tt;
    if (rem >= 2)      asm volatile("s_waitcnt vmcnt(8)" ::: "memory");
    else if (rem == 1) asm volatile("s_waitcnt vmcnt(4)" ::: "memory");
    else               asm volatile("s_waitcnt vmcnt(0)" ::: "memory");
    __builtin_amdgcn_s_barrier();
    __builtin_amdgcn_sched_barrier(0);

    if (tt == ntA) { // segment switch: flush A, reset state, load Q for B
      finalize();
#pragma unroll
      for (int dt = 0; dt < 8; ++dt) o[dt] = (f32x4){0.f, 0.f, 0.f, 0.f};
      m = -__builtin_inff();
      lsum = 0.0f;
      qbw = qtB * 128 + wid * 16;
#pragma unroll
      for (int c = 0; c < 4; ++c)
        aq[c] = *(const bf16x8*)(qptr + (size_t)(qbw + l16) * HD + c * 32 + lk4 * 8);
    }

    int k0 = k0_of(tt);
    int buf = tt & 3;
    if (k0 < qbw + 16) { // this wave has unmasked keys in this tile
      const char* Kbase = (const char*)&lK[buf][0];
      const char* Vbase = (const char*)&lV[buf][0];
      f32x4 s[4] = {};
      __builtin_amdgcn_s_setprio(1);
#pragma unroll
      for (int c = 0; c < 4; ++c) {
#pragma unroll
        for (int t = 0; t < 4; ++t) {
          bf16x8 bk = *(const bf16x8*)(Kbase + (t * 16 + l16) * 256 + ((c * 64 + lk4 * 16) ^ swzk));
          s[t] = __builtin_amdgcn_mfma_f32_16x16x32_bf16(bk, aq[c], s[t], 0, 0, 0);
        }
      }
      __builtin_amdgcn_s_setprio(0);
      float x[16];
#pragma unroll
      for (int t = 0; t < 4; ++t)
#pragma unroll
        for (int j = 0; j < 4; ++j) x[t * 4 + j] = s[t][j];
      if (k0 + 63 > qbw) { // tile touches this wave's causal diagonal
        int kq = k0 + lk4 * 4 - qbw - l16;
#pragma unroll
        for (int t = 0; t < 4; ++t)
#pragma unroll
          for (int j = 0; j < 4; ++j)
            if (kq + t * 16 + j > 0) x[t * 4 + j] = -3.0e38f;
      }
      float a0 = fmaxf(x[0], x[1]), a1 = fmaxf(x[2], x[3]);
      float a2 = fmaxf(x[4], x[5]), a3 = fmaxf(x[6], x[7]);
      float a4 = fmaxf(x[8], x[9]), a5 = fmaxf(x[10], x[11]);
      float a6 = fmaxf(x[12], x[13]), a7 = fmaxf(x[14], x[15]);
      float b0 = fmaxf(fmaxf(a0, a1), fmaxf(a2, a3));
      float b1 = fmaxf(fmaxf(a4, a5), fmaxf(a6, a7));
      float tm = fmaxf(b0, b1);
      tm = fmaxf(tm, __shfl_xor(tm, 16));
      tm = fmaxf(tm, __shfl_xor(tm, 32));
      float mn = fmaxf(m, tm);
      if (!__all(tm <= m + 8.0f)) { // T13 defer-rescale
        float f = __builtin_amdgcn_exp2f(m - mn);
        m = mn;
        lsum *= f;
#pragma unroll
        for (int dt = 0; dt < 8; ++dt) o[dt] *= f;
      }
      float psum = 0.0f;
#pragma unroll
      for (int t = 0; t < 4; ++t) {
        float p0 = __builtin_amdgcn_exp2f(x[t * 4 + 0] - m);
        float p1 = __builtin_amdgcn_exp2f(x[t * 4 + 1] - m);
        float p2 = __builtin_amdgcn_exp2f(x[t * 4 + 2] - m);
        float p3 = __builtin_amdgcn_exp2f(x[t * 4 + 3] - m);
        psum += (p0 + p1) + (p2 + p3);
        unsigned lo, hi;
        asm("v_cvt_pk_bf16_f32 %0, %1, %2" : "=v"(lo) : "v"(p0), "v"(p1));
        asm("v_cvt_pk_bf16_f32 %0, %1, %2" : "=v"(hi) : "v"(p2), "v"(p3));
        unsigned long long dw = ((unsigned long long)hi << 32) | lo;
        *(unsigned long long*)(myP + ((l16 * 128 + t * 32 + lk4 * 8) ^ swz)) = dw;
      }
      lsum += psum;
      // ---- ORDERING FENCE (rule #18): drain P ds_writes, pin reads below --
      asm volatile("s_waitcnt lgkmcnt(0)" ::: "memory");
      __builtin_amdgcn_sched_barrier(0);
      __builtin_amdgcn_s_setprio(1);
#pragma unroll
      for (int hh = 0; hh < 2; ++hh) {
        bf16x8 pa = *(const bf16x8*)(myP + ((l16 * 128 + hh * 64 + lk4 * 16) ^ swz));
#pragma unroll
        for (int dt = 0; dt < 8; ++dt) {
          bf16x8 bv = *(const bf16x8*)(Vbase + (dt * 16 + l16) * 128 + ((hh * 64 + lk4 * 16) ^ swz));
          o[dt] = __builtin_amdgcn_mfma_f32_16x16x32_bf16(bv, pa, o[dt], 0, 0, 0);
        }
      }
      __builtin_amdgcn_s_setprio(0);
    }
    // issue stage for tile tt+3 into ring slot (tt+3)&3 == (tt-1)&3, whose
    // readers finished before this iteration's opening barrier (no WAR race).
    if (tt + 3 < ntot) stageKV((tt + 3) & 3, k0_of(tt + 3));
  }
  finalize(); // segment B
}

extern "C" void kernel_launch(void* const* d_in, const int* in_sizes, int n_in,
                              void* d_out, int out_size, void* d_ws, size_t ws_size,
                              hipStream_t stream) {
  const float* x  = (const float*)d_in[0];
  const float* wq = (const float*)d_in[1];
  const float* wk = (const float*)d_in[2];
  const float* wv = (const float*)d_in[3];
  const float* wo = (const float*)d_in[4];
  float* out = (float*)d_out;
  char* ws = (char*)d_ws;
  (void)in_sizes; (void)n_in; (void)out_size; (void)ws_size;

  const size_t MB = 1024 * 1024;
  f32x2* rope   = (f32x2*)(ws);          // 1 MB
  short* xb     = (short*)(ws + 1 * MB); // 16 MB (reused as O)
  short* wqkvT  = (short*)(ws + 17 * MB);// 12 MB: [3072][2048] bf16 B^T
  short* woT    = (short*)(ws + 29 * MB);// 8 MB
  short* QKVb   = (short*)(ws + 37 * MB);// 24 MB: Q(16) + K(4) + V(4)
  short* O      = xb;                    // alias: xb dead after QKV GEMM

  short* Qb = QKVb;
  short* Kb = QKVb + QOFF;
  short* Vt = QKVb + QOFF + KOFF;

  prep_k<<<PB5, 256, 0, stream>>>(x, wq, wk, wv, wo, rope, xb, wqkvT, woT);

  gemm_bt_k<5><<<dim3(MROWS / 128, 3072 / 128), 256, 0, stream>>>(xb, wqkvT, nullptr, QKVb, MROWS, 3072, 2048, rope);

  flash_k<<<256, 512, 0, stream>>>(Qb, Kb, Vt, O);

  gemm_bt_k<0><<<dim3(MROWS / 128, 2048 / 128), 256, 0, stream>>>(O, woT, out, nullptr, MROWS, 2048, 2048, rope);
}